// Round 12
// baseline (151.806 us; speedup 1.0000x reference)
//
#include <hip/hip_runtime.h>
#include <cstdint>
#include <cstddef>

typedef _Float16 f16x8 __attribute__((ext_vector_type(8)));
typedef float f32x4 __attribute__((ext_vector_type(4)));

#define N_ROWS 8192
#define SPAN   8187u   // n - k
#define MULT   1600u   // (2^32) % 8187
#define TAU_INV 10.0f
#define TOTAL_SAMP 163840u
#define INIT32 0xFFFFFFFFu

// ---------------- threefry2x32 (JAX-compatible) ----------------
__device__ __forceinline__ void tf_round(unsigned &x0, unsigned &x1, int r) {
    x0 += x1; x1 = (x1 << r) | (x1 >> (32 - r)); x1 ^= x0;
}
__device__ __forceinline__ void threefry2x32(unsigned k0, unsigned k1,
                                             unsigned c0, unsigned c1,
                                             unsigned &o0, unsigned &o1) {
    unsigned ks2 = k0 ^ k1 ^ 0x1BD11BDAu;
    unsigned x0 = c0 + k0, x1 = c1 + k1;
    tf_round(x0, x1, 13); tf_round(x0, x1, 15); tf_round(x0, x1, 26); tf_round(x0, x1, 6);
    x0 += k1;  x1 += ks2 + 1u;
    tf_round(x0, x1, 17); tf_round(x0, x1, 29); tf_round(x0, x1, 16); tf_round(x0, x1, 24);
    x0 += ks2; x1 += k0 + 2u;
    tf_round(x0, x1, 13); tf_round(x0, x1, 15); tf_round(x0, x1, 26); tf_round(x0, x1, 6);
    x0 += k0;  x1 += k1 + 3u;
    tf_round(x0, x1, 17); tf_round(x0, x1, 29); tf_round(x0, x1, 16); tf_round(x0, x1, 24);
    x0 += k1;  x1 += ks2 + 4u;
    tf_round(x0, x1, 13); tf_round(x0, x1, 15); tf_round(x0, x1, 26); tf_round(x0, x1, 6);
    x0 += ks2; x1 += k0 + 5u;
    o0 = x0; o1 = x1;
}

// ---------------- async global->LDS (16B), offset folded into pointers ----------------
// NOTE (round-4 lesson): never use the builtin's imm-offset arg; fold into pointers.
// LDS dest is wave-uniform base + lane*16 (HW); global src is per-lane.
__device__ __forceinline__ void async16(void* lds, const void* g) {
    __builtin_amdgcn_global_load_lds((const __attribute__((address_space(1))) void*)g,
                                     (__attribute__((address_space(3))) void*)lds, 16, 0, 0);
}

// Stage 1KB chunk q of an N-row x 64-col f16 tile (row-major, 128 B/row), XOR-swizzled
// source chunk so LDS dest stays lane-linear. LDS slot (r,c) = global chunk c^(r&7).
__device__ __forceinline__ void stage_chunk(char* lds_tile, const char* gtile, int q, int lane) {
    int off16 = (q << 6) + lane;
    int r = off16 >> 3;
    int slot = off16 & 7;
    int csrc = slot ^ (r & 7);
    async16(lds_tile + (q << 10), gtile + r * 128 + (csrc << 4));
}

__device__ __forceinline__ f16x8 read_frag(const char* tile, int row, int c) {
    return *(const f16x8*)(tile + row * 128 + (((c ^ (row & 7)) << 4)));
}

// single-instruction unsigned median-of-3
__device__ __forceinline__ unsigned umed3(unsigned a, unsigned b, unsigned c) {
    unsigned d;
    asm("v_med3_u32 %0, %1, %2, %3" : "=v"(d) : "v"(a), "v"(b), "v"(c));
    return d;
}

__device__ __forceinline__ float wave_maxf(float v) {
#pragma unroll
    for (int o = 32; o; o >>= 1) v = fmaxf(v, __shfl_xor(v, o));
    return v;
}
__device__ __forceinline__ float wave_sumf(float v) {
#pragma unroll
    for (int o = 32; o; o >>= 1) v += __shfl_xor(v, o);
    return v;
}
__device__ __forceinline__ unsigned wave_minu32(unsigned v) {
#pragma unroll
    for (int o = 32; o; o >>= 1) {
        unsigned w = (unsigned)__shfl_xor((int)v, o);
        v = (w < v) ? w : v;
    }
    return v;
}
// min over the 16-lane group (lanes sharing lq => sharing rows)
__device__ __forceinline__ unsigned group_minu32(unsigned v) {
#pragma unroll
    for (int o = 8; o; o >>= 1) {
        unsigned w = (unsigned)__shfl_xor((int)v, o);
        v = (w < v) ? w : v;
    }
    return v;
}

// ---------------- Kernel 1: norms + f16 cast (+ zero reduction slots) ----------------
__global__ void prep_kernel(const float* __restrict__ X,
                            float2* __restrict__ nsiv,
                            char* __restrict__ Xf,
                            float* __restrict__ ws8,
                            unsigned* __restrict__ cnt) {
    if (blockIdx.x == 0 && threadIdx.x < 9) {
        if (threadIdx.x < 8) ws8[threadIdx.x] = 0.f;
        else *cnt = 0u;
    }
    int t = blockIdx.x * 256 + threadIdx.x;
    int row = t >> 3, c = t & 7;
    const float4* src = (const float4*)(X + (size_t)row * 64 + c * 8);
    float4 a = src[0], b = src[1];
    float v[8] = {a.x, a.y, a.z, a.w, b.x, b.y, b.z, b.w};
    float ss = 0.f;
#pragma unroll
    for (int j = 0; j < 8; ++j) ss = fmaf(v[j], v[j], ss);
    ss += __shfl_xor(ss, 1);
    ss += __shfl_xor(ss, 2);
    ss += __shfl_xor(ss, 4);
    f16x8 h;
#pragma unroll
    for (int j = 0; j < 8; ++j) h[j] = (_Float16)v[j];
    *(f16x8*)(Xf + (size_t)row * 128 + c * 16) = h;
    if (c == 0) nsiv[row] = make_float2(ss, 1.0f / (1.0f - fminf(ss, 1.0f)));
}

// ---------------- Kernel 2: MFMA gram + fused top-5, 3-buffer counted-vmcnt ----------------
// v11 (unchanged): 128-row x 512-col blocks, grid 1024, 8 iters. Staging runs 2 tiles
// ahead into 3 x 8KB buffers; per iter: barrier1 -> stage(t+2) -> vmcnt(4) -> barrier2
// -> compute. vmcnt FIFO holds ONLY staging loads (norms cached in LDS).
__global__ __launch_bounds__(256, 3) void gram_topk(
        const char* __restrict__ Xf,
        const float2* __restrict__ nsiv, unsigned* __restrict__ part) {
    __shared__ __align__(16) char lds[29696];   // 3x8KB B-bufs | 4KB col-nsiv | 1KB row-nsiv

    const int t = threadIdx.x, lane = t & 63, wv = t >> 6;
    const int lx = lane & 15, lq = lane >> 4;
    const int r0 = (blockIdx.x >> 4) * 128;
    const int ch = blockIdx.x & 15;
    const int j0base = ch * 512;

    // ---- prologue: stage A (16KB @0), col-nsiv cache (4KB @24576), row-nsiv (1KB @28672)
    const char* gA = Xf + (size_t)r0 * 128;
#pragma unroll
    for (int q = 0; q < 4; ++q) stage_chunk(lds, gA, 4 * wv + q, lane);
    async16(lds + 24576 + wv * 1024, (const char*)(nsiv + j0base) + wv * 1024 + lane * 16);
    if (wv == 0) async16(lds + 28672, (const char*)(nsiv + r0) + lane * 16);
    __syncthreads();   // full vmcnt drain + barrier: FIFO empty after this

    f16x8 a0f[2], a1f[2];
#pragma unroll
    for (int kc = 0; kc < 2; ++kc) {
        a0f[kc] = read_frag(lds, wv * 32 +      lx, kc * 4 + lq);
        a1f[kc] = read_frag(lds, wv * 32 + 16 + lx, kc * 4 + lq);
    }
    // row norms from LDS cache (ds_read; keeps the vmcnt FIFO staging-only)
    const float2* rowns = (const float2*)(lds + 28672);
    float rns0[4], rns1[4];
#pragma unroll
    for (int r = 0; r < 4; ++r) {
        rns0[r] = rowns[wv * 32 + lq * 4 + r].x;
        rns1[r] = rowns[wv * 32 + lq * 4 + r + 16].x;
    }
    const int jlx = j0base + lx;
    const int dg  = (r0 + wv * 32 + lq * 4) - jlx;   // diag when dofs - r (+16) == dg
    __syncthreads();   // all waves done reading A region; buf0/1 reusable

    // stage tiles 0 -> buf0 and 1 -> buf1 (per-lane swizzled source)
    const int rA  = 16 * wv + (lane >> 3);
    const int csA = (lane & 7) ^ ((lane >> 3) & 7);
    const char* gb = Xf + (size_t)j0base * 128 + rA * 128 + (csA << 4);
    async16(lds +        wv * 2048,        gb);
    async16(lds +        wv * 2048 + 1024, gb + 1024);
    gb += 8192;
    async16(lds + 8192 + wv * 2048,        gb);
    async16(lds + 8192 + wv * 2048 + 1024, gb + 1024);
    gb += 8192;                                      // gb -> tile 2

    const char* pB0  = lds + lx * 128 + ((lq       ^ (lx & 7)) << 4);
    const char* pB1  = lds + lx * 128 + (((4 + lq) ^ (lx & 7)) << 4);
    const char* pnlp = lds + 24576 + lx * 8;         // col-nsiv cache walker

    unsigned tk0[4][5], tk1[4][5];
#pragma unroll
    for (int r = 0; r < 4; ++r)
#pragma unroll
        for (int s = 0; s < 5; ++s) { tk0[r][s] = INIT32; tk1[r][s] = INIT32; }

    int itofs = 0;

#define INS5(TK, KK)                                                          \
    TK[4] = umed3(TK[3], TK[4], KK);                                          \
    TK[3] = umed3(TK[2], TK[3], KK);                                          \
    TK[2] = umed3(TK[1], TK[2], KK);                                          \
    TK[1] = umed3(TK[0], TK[1], KK);                                          \
    TK[0] = (KK < TK[0]) ? KK : TK[0];

#define ITER(RSEL, SSEL, DO_STAGE, VMSTR) do {                                \
    asm volatile("" ::: "memory");                                            \
    __builtin_amdgcn_s_barrier();      /* barrier1: all readers of SSEL done */\
    asm volatile("" ::: "memory");                                            \
    if (DO_STAGE) {                                                           \
        async16(lds + (SSEL) + wv * 2048,        gb);                         \
        async16(lds + (SSEL) + wv * 2048 + 1024, gb + 1024);                  \
        gb += 8192;                                                           \
    }                                                                         \
    asm volatile("s_waitcnt vmcnt(" VMSTR ")" ::: "memory");                  \
    __builtin_amdgcn_s_barrier();      /* barrier2: tile t landed (all waves)*/\
    asm volatile("" ::: "memory");                                            \
    _Pragma("unroll")                                                         \
    for (int ct = 0; ct < 4; ++ct) {                                          \
        const f16x8 bh0 = *(const f16x8*)(pB0 + (RSEL) + ct * 2048);          \
        const f16x8 bh1 = *(const f16x8*)(pB1 + (RSEL) + ct * 2048);          \
        f32x4 a0 = {0.f, 0.f, 0.f, 0.f};                                      \
        f32x4 a1 = {0.f, 0.f, 0.f, 0.f};                                      \
        a0 = __builtin_amdgcn_mfma_f32_16x16x32_f16(a0f[0], bh0, a0, 0,0,0);  \
        a1 = __builtin_amdgcn_mfma_f32_16x16x32_f16(a1f[0], bh0, a1, 0,0,0);  \
        a0 = __builtin_amdgcn_mfma_f32_16x16x32_f16(a0f[1], bh1, a0, 0,0,0);  \
        a1 = __builtin_amdgcn_mfma_f32_16x16x32_f16(a1f[1], bh1, a1, 0,0,0);  \
        const float2 cn = *(const float2*)(pnlp + ct * 128);                  \
        const float civ    = cn.y;                                            \
        const float cnsciv = cn.x * civ;                                      \
        const float m2civ  = -2.0f * civ;                                     \
        const unsigned gcol = (unsigned)(jlx + itofs + ct * 16);              \
        const int dofs = itofs + ct * 16;                                     \
        _Pragma("unroll")                                                     \
        for (int r = 0; r < 4; ++r) {                                         \
            float q0 = fmaf(a0[r], m2civ, fmaf(rns0[r], civ, cnsciv));        \
            q0 = fmaxf(q0, 0.0f);                                             \
            unsigned k0 = (__float_as_uint(q0) & 0xFFFFE000u) | gcol;         \
            k0 = (dofs - r == dg) ? INIT32 : k0;                              \
            INS5(tk0[r], k0)                                                  \
            float q1 = fmaf(a1[r], m2civ, fmaf(rns1[r], civ, cnsciv));        \
            q1 = fmaxf(q1, 0.0f);                                             \
            unsigned k1 = (__float_as_uint(q1) & 0xFFFFE000u) | gcol;         \
            k1 = (dofs - r - 16 == dg) ? INIT32 : k1;                         \
            INS5(tk1[r], k1)                                                  \
        }                                                                     \
    }                                                                         \
    itofs += 64;                                                              \
    pnlp  += 512;                                                             \
    asm volatile("" ::: "memory");                                            \
} while (0)

    // steady state t=0..5 (stage t+2, wait own tile with 4 newer in flight)
#pragma unroll 1
    for (int ip = 0; ip < 2; ++ip) {
        ITER(0,     16384, true, "4");   // t: buf0, stage -> buf2
        ITER(8192,  0,     true, "4");   // t: buf1, stage -> buf0
        ITER(16384, 8192,  true, "4");   // t: buf2, stage -> buf1
    }
    // epilogue t=6 (outstanding t6,t7), t=7 (outstanding t7)
    ITER(0,    0, false, "2");
    ITER(8192, 0, false, "0");
#undef ITER
#undef INS5

    // ---- in-register merge: 16 lanes x sorted-5 -> row top-5, 5 rounds of group-min ----
    // keys unique across lanes (col mod 16 == lx), so exactly the winner advances.
#define MERGE(TK, ROWOFS) do {                                                \
    _Pragma("unroll")                                                         \
    for (int r = 0; r < 4; ++r) {                                             \
        unsigned t5r[5];                                                      \
        _Pragma("unroll")                                                     \
        for (int s = 0; s < 5; ++s) t5r[s] = TK[r][s];                        \
        unsigned out = INIT32;                                                \
        unsigned h = t5r[0];                                                  \
        _Pragma("unroll")                                                     \
        for (int s = 0; s < 5; ++s) {                                         \
            unsigned m = group_minu32(h);                                     \
            if (lx == s) out = m;                                             \
            if (h == m) {                                                     \
                t5r[0] = t5r[1]; t5r[1] = t5r[2]; t5r[2] = t5r[3];            \
                t5r[3] = t5r[4]; t5r[4] = INIT32;                             \
                h = t5r[0];                                                   \
            }                                                                 \
        }                                                                     \
        if (lx < 5)                                                           \
            part[(size_t)(r0 + wv * 32 + lq * 4 + r + (ROWOFS)) * 80          \
                 + (size_t)ch * 5 + lx] = out;                                \
    }                                                                         \
} while (0)

    MERGE(tk0, 0);
    MERGE(tk1, 16);
#undef MERGE
}

// ---------------- Kernel 3: finalize (r8 shape) + fused final reduction ----------------
// 2048 blocks x 256 (1 row/wave — proven fast). Per-block partial -> atomicAdd into
// 8 spread slots + counter; last block (cnt==2047) sums slots and writes out.
// Slots/counter zeroed by prep each replay (stream-ordered).
__global__ __launch_bounds__(256) void finalize_kernel(
        const float* __restrict__ X, const float2* __restrict__ nsiv,
        const unsigned* __restrict__ part, float* __restrict__ ws8,
        unsigned* __restrict__ cnt, float* __restrict__ out) {
    const int t = threadIdx.x, lane = t & 63, wv = t >> 6;
    const int row = blockIdx.x * 4 + wv;

    // merge chunk top-5s (80 u32 keys, 2 per lane) -> global top-5 via 5 wave-min passes
    const unsigned* prow = part + (size_t)row * 80;
    unsigned a0 = prow[lane];
    unsigned a1 = (lane < 16) ? prow[64 + lane] : INIT32;
    unsigned klo = (a0 < a1) ? a0 : a1;
    unsigned khi = (a0 < a1) ? a1 : a0;
    unsigned b[5];
#pragma unroll
    for (int s = 0; s < 5; ++s) {
        unsigned m = wave_minu32(klo);
        b[s] = m;
        if (klo == m) { klo = khi; khi = INIT32; }   // unique keys -> unique min
    }

    int pcol[5], ids[5];
#pragma unroll
    for (int s = 0; s < 5; ++s) { pcol[s] = (int)(b[s] & 8191u); ids[s] = pcol[s]; }
    // sort excluded ids ascending (tiny; every lane duplicates)
    for (int i = 0; i < 4; ++i)
        for (int j = 0; j < 4 - i; ++j)
            if (ids[j] > ids[j + 1]) { int tmp = ids[j]; ids[j] = ids[j + 1]; ids[j + 1] = tmp; }

    // column for this lane: lanes 0..19 = sampled negatives, 20..24 = positives
    int col = row;
    if (lane < 20) {
        unsigned m0 = (unsigned)(row * 20 + lane);
        unsigned hi, lo;
        threefry2x32(0u, 42u, m0, m0 + TOTAL_SAMP, hi, lo);
        unsigned samp = ((hi % SPAN) * MULT + (lo % SPAN)) % SPAN;
        int c = (int)samp;
#pragma unroll
        for (int s = 0; s < 5; ++s) c += (ids[s] <= c) ? 1 : 0;
        col = c;
    } else if (lane < 25) {
        col = pcol[lane - 20];
    }

    // exact fp32 Poincare distance term  -dist/tau  (diagonal -> -inf)
    float term = -INFINITY;
    if (lane < 25 && col != row) {
        const float4* xr = (const float4*)(X + (size_t)row * 64);
        const float4* xc = (const float4*)(X + (size_t)col * 64);
        float dot = 0.f;
#pragma unroll
        for (int k = 0; k < 16; ++k) {
            float4 a = xr[k];
            float4 c = xc[k];
            dot = fmaf(a.x, c.x, dot);
            dot = fmaf(a.y, c.y, dot);
            dot = fmaf(a.z, c.z, dot);
            dot = fmaf(a.w, c.w, dot);
        }
        float nsi = nsiv[row].x, nsj = nsiv[col].x;
        float d2  = fmaxf(nsi + nsj - 2.f * dot, 0.f);
        float ci  = 1.f - fminf(nsi, 1.f);
        float cj  = 1.f - fminf(nsj, 1.f);
        float den = fmaxf(ci * cj, 1e-9f);
        float z   = fmaxf(1.f + 2.f * d2 / den, 1.f);
        term = -acoshf(z) * TAU_INV;
    }

    // two masked LSEs across the wave
    float negt = (lane < 20) ? term : -INFINITY;
    float post = (lane >= 20 && lane < 25) ? term : -INFINITY;

    float nm = wave_maxf(negt);
    float ne = (lane < 20 && negt != -INFINITY) ? expf(negt - nm) : 0.f;
    float neg = nm + logf(wave_sumf(ne));

    float pm = wave_maxf(post);
    float pe = (lane >= 20 && lane < 25) ? expf(post - pm) : 0.f;
    float pos = pm + logf(wave_sumf(pe));

    __shared__ float ws4[4];
    if (lane == 0) ws4[wv] = neg - pos;
    __syncthreads();
    if (t == 0) {
        atomicAdd(&ws8[blockIdx.x & 7], ws4[0] + ws4[1] + ws4[2] + ws4[3]);
        __threadfence();
        unsigned old = atomicAdd(cnt, 1u);
        if (old == 2047u) {
            float tot = 0.f;
#pragma unroll
            for (int i = 0; i < 8; ++i) tot += atomicAdd(&ws8[i], 0.0f);  // coherent read
            out[0] = tot * (1.0f / 8192.0f);
        }
    }
}

// ---------------- launch ----------------
extern "C" void kernel_launch(void* const* d_in, const int* in_sizes, int n_in,
                              void* d_out, int out_size, void* d_ws, size_t ws_size,
                              hipStream_t stream) {
    (void)in_sizes; (void)n_in; (void)out_size; (void)ws_size;
    const float* X = (const float*)d_in[0];
    float* out = (float*)d_out;

    float2*   nsiv = (float2*)d_ws;                                  // 64 KB
    char*     Xf   = (char*)d_ws + 65536;                            // 1 MB
    unsigned* part = (unsigned*)((char*)d_ws + 65536 + 1048576);     // 2.62 MB (8192*80*4)
    float*    ws8  = (float*)((char*)d_ws + 65536 + 1048576 + 2621440);        // 32 B
    unsigned* cnt  = (unsigned*)((char*)d_ws + 65536 + 1048576 + 2621440 + 32); // 4 B

    prep_kernel<<<256, 256, 0, stream>>>(X, nsiv, Xf, ws8, cnt);
    gram_topk<<<1024, 256, 0, stream>>>(Xf, nsiv, part);
    finalize_kernel<<<2048, 256, 0, stream>>>(X, nsiv, part, ws8, cnt, out);
}

// Round 13
// 103.797 us; speedup vs baseline: 1.4625x; 1.4625x over previous
//
#include <hip/hip_runtime.h>
#include <cstdint>
#include <cstddef>

typedef _Float16 f16x8 __attribute__((ext_vector_type(8)));
typedef float f32x4 __attribute__((ext_vector_type(4)));

#define N_ROWS 8192
#define SPAN   8187u   // n - k
#define MULT   1600u   // (2^32) % 8187
#define TAU_INV 10.0f
#define TOTAL_SAMP 163840u
#define INIT32 0xFFFFFFFFu

// ---------------- threefry2x32 (JAX-compatible) ----------------
__device__ __forceinline__ void tf_round(unsigned &x0, unsigned &x1, int r) {
    x0 += x1; x1 = (x1 << r) | (x1 >> (32 - r)); x1 ^= x0;
}
__device__ __forceinline__ void threefry2x32(unsigned k0, unsigned k1,
                                             unsigned c0, unsigned c1,
                                             unsigned &o0, unsigned &o1) {
    unsigned ks2 = k0 ^ k1 ^ 0x1BD11BDAu;
    unsigned x0 = c0 + k0, x1 = c1 + k1;
    tf_round(x0, x1, 13); tf_round(x0, x1, 15); tf_round(x0, x1, 26); tf_round(x0, x1, 6);
    x0 += k1;  x1 += ks2 + 1u;
    tf_round(x0, x1, 17); tf_round(x0, x1, 29); tf_round(x0, x1, 16); tf_round(x0, x1, 24);
    x0 += ks2; x1 += k0 + 2u;
    tf_round(x0, x1, 13); tf_round(x0, x1, 15); tf_round(x0, x1, 26); tf_round(x0, x1, 6);
    x0 += k0;  x1 += k1 + 3u;
    tf_round(x0, x1, 17); tf_round(x0, x1, 29); tf_round(x0, x1, 16); tf_round(x0, x1, 24);
    x0 += k1;  x1 += ks2 + 4u;
    tf_round(x0, x1, 13); tf_round(x0, x1, 15); tf_round(x0, x1, 26); tf_round(x0, x1, 6);
    x0 += ks2; x1 += k0 + 5u;
    o0 = x0; o1 = x1;
}

// ---------------- async global->LDS (16B), offset folded into pointers ----------------
// NOTE (round-4 lesson): never use the builtin's imm-offset arg; fold into pointers.
// LDS dest is wave-uniform base + lane*16 (HW); global src is per-lane.
__device__ __forceinline__ void async16(void* lds, const void* g) {
    __builtin_amdgcn_global_load_lds((const __attribute__((address_space(1))) void*)g,
                                     (__attribute__((address_space(3))) void*)lds, 16, 0, 0);
}

// Stage 1KB chunk q of an N-row x 64-col f16 tile (row-major, 128 B/row), XOR-swizzled
// source chunk so LDS dest stays lane-linear. LDS slot (r,c) = global chunk c^(r&7).
__device__ __forceinline__ void stage_chunk(char* lds_tile, const char* gtile, int q, int lane) {
    int off16 = (q << 6) + lane;
    int r = off16 >> 3;
    int slot = off16 & 7;
    int csrc = slot ^ (r & 7);
    async16(lds_tile + (q << 10), gtile + r * 128 + (csrc << 4));
}

__device__ __forceinline__ f16x8 read_frag(const char* tile, int row, int c) {
    return *(const f16x8*)(tile + row * 128 + (((c ^ (row & 7)) << 4)));
}

// single-instruction unsigned median-of-3
__device__ __forceinline__ unsigned umed3(unsigned a, unsigned b, unsigned c) {
    unsigned d;
    asm("v_med3_u32 %0, %1, %2, %3" : "=v"(d) : "v"(a), "v"(b), "v"(c));
    return d;
}

__device__ __forceinline__ float wave_maxf(float v) {
#pragma unroll
    for (int o = 32; o; o >>= 1) v = fmaxf(v, __shfl_xor(v, o));
    return v;
}
__device__ __forceinline__ float wave_sumf(float v) {
#pragma unroll
    for (int o = 32; o; o >>= 1) v += __shfl_xor(v, o);
    return v;
}
__device__ __forceinline__ unsigned wave_minu32(unsigned v) {
#pragma unroll
    for (int o = 32; o; o >>= 1) {
        unsigned w = (unsigned)__shfl_xor((int)v, o);
        v = (w < v) ? w : v;
    }
    return v;
}
// min over the 16-lane group (lanes sharing lq => sharing rows)
__device__ __forceinline__ unsigned group_minu32(unsigned v) {
#pragma unroll
    for (int o = 8; o; o >>= 1) {
        unsigned w = (unsigned)__shfl_xor((int)v, o);
        v = (w < v) ? w : v;
    }
    return v;
}

// ---------------- Kernel 1: norms + f16 cast ----------------
__global__ void prep_kernel(const float* __restrict__ X,
                            float2* __restrict__ nsiv,
                            char* __restrict__ Xf) {
    int t = blockIdx.x * 256 + threadIdx.x;
    int row = t >> 3, c = t & 7;
    const float4* src = (const float4*)(X + (size_t)row * 64 + c * 8);
    float4 a = src[0], b = src[1];
    float v[8] = {a.x, a.y, a.z, a.w, b.x, b.y, b.z, b.w};
    float ss = 0.f;
#pragma unroll
    for (int j = 0; j < 8; ++j) ss = fmaf(v[j], v[j], ss);
    ss += __shfl_xor(ss, 1);
    ss += __shfl_xor(ss, 2);
    ss += __shfl_xor(ss, 4);
    f16x8 h;
#pragma unroll
    for (int j = 0; j < 8; ++j) h[j] = (_Float16)v[j];
    *(f16x8*)(Xf + (size_t)row * 128 + c * 16) = h;
    if (c == 0) nsiv[row] = make_float2(ss, 1.0f / (1.0f - fminf(ss, 1.0f)));
}

// ---------------- Kernel 2: MFMA gram + fused top-5, 3-buffer counted-vmcnt ----------------
// v11 + s_setprio around the compute phase (T5: pays only on phase-split schedules,
// which v11's stage/compute role split now is; isolated delta vs r11's 104.6 us).
__global__ __launch_bounds__(256, 3) void gram_topk(
        const char* __restrict__ Xf,
        const float2* __restrict__ nsiv, unsigned* __restrict__ part) {
    __shared__ __align__(16) char lds[29696];   // 3x8KB B-bufs | 4KB col-nsiv | 1KB row-nsiv

    const int t = threadIdx.x, lane = t & 63, wv = t >> 6;
    const int lx = lane & 15, lq = lane >> 4;
    const int r0 = (blockIdx.x >> 4) * 128;
    const int ch = blockIdx.x & 15;
    const int j0base = ch * 512;

    // ---- prologue: stage A (16KB @0), col-nsiv cache (4KB @24576), row-nsiv (1KB @28672)
    const char* gA = Xf + (size_t)r0 * 128;
#pragma unroll
    for (int q = 0; q < 4; ++q) stage_chunk(lds, gA, 4 * wv + q, lane);
    async16(lds + 24576 + wv * 1024, (const char*)(nsiv + j0base) + wv * 1024 + lane * 16);
    if (wv == 0) async16(lds + 28672, (const char*)(nsiv + r0) + lane * 16);
    __syncthreads();   // full vmcnt drain + barrier: FIFO empty after this

    f16x8 a0f[2], a1f[2];
#pragma unroll
    for (int kc = 0; kc < 2; ++kc) {
        a0f[kc] = read_frag(lds, wv * 32 +      lx, kc * 4 + lq);
        a1f[kc] = read_frag(lds, wv * 32 + 16 + lx, kc * 4 + lq);
    }
    // row norms from LDS cache (ds_read; keeps the vmcnt FIFO staging-only)
    const float2* rowns = (const float2*)(lds + 28672);
    float rns0[4], rns1[4];
#pragma unroll
    for (int r = 0; r < 4; ++r) {
        rns0[r] = rowns[wv * 32 + lq * 4 + r].x;
        rns1[r] = rowns[wv * 32 + lq * 4 + r + 16].x;
    }
    const int jlx = j0base + lx;
    const int dg  = (r0 + wv * 32 + lq * 4) - jlx;   // diag when dofs - r (+16) == dg
    __syncthreads();   // all waves done reading A region; buf0/1 reusable

    // stage tiles 0 -> buf0 and 1 -> buf1 (per-lane swizzled source)
    const int rA  = 16 * wv + (lane >> 3);
    const int csA = (lane & 7) ^ ((lane >> 3) & 7);
    const char* gb = Xf + (size_t)j0base * 128 + rA * 128 + (csA << 4);
    async16(lds +        wv * 2048,        gb);
    async16(lds +        wv * 2048 + 1024, gb + 1024);
    gb += 8192;
    async16(lds + 8192 + wv * 2048,        gb);
    async16(lds + 8192 + wv * 2048 + 1024, gb + 1024);
    gb += 8192;                                      // gb -> tile 2

    const char* pB0  = lds + lx * 128 + ((lq       ^ (lx & 7)) << 4);
    const char* pB1  = lds + lx * 128 + (((4 + lq) ^ (lx & 7)) << 4);
    const char* pnlp = lds + 24576 + lx * 8;         // col-nsiv cache walker

    unsigned tk0[4][5], tk1[4][5];
#pragma unroll
    for (int r = 0; r < 4; ++r)
#pragma unroll
        for (int s = 0; s < 5; ++s) { tk0[r][s] = INIT32; tk1[r][s] = INIT32; }

    int itofs = 0;

#define INS5(TK, KK)                                                          \
    TK[4] = umed3(TK[3], TK[4], KK);                                          \
    TK[3] = umed3(TK[2], TK[3], KK);                                          \
    TK[2] = umed3(TK[1], TK[2], KK);                                          \
    TK[1] = umed3(TK[0], TK[1], KK);                                          \
    TK[0] = (KK < TK[0]) ? KK : TK[0];

#define ITER(RSEL, SSEL, DO_STAGE, VMSTR) do {                                \
    asm volatile("" ::: "memory");                                            \
    __builtin_amdgcn_s_barrier();      /* barrier1: all readers of SSEL done */\
    asm volatile("" ::: "memory");                                            \
    if (DO_STAGE) {                                                           \
        async16(lds + (SSEL) + wv * 2048,        gb);                         \
        async16(lds + (SSEL) + wv * 2048 + 1024, gb + 1024);                  \
        gb += 8192;                                                           \
    }                                                                         \
    asm volatile("s_waitcnt vmcnt(" VMSTR ")" ::: "memory");                  \
    __builtin_amdgcn_s_barrier();      /* barrier2: tile t landed (all waves)*/\
    asm volatile("" ::: "memory");                                            \
    __builtin_amdgcn_s_setprio(1);                                            \
    _Pragma("unroll")                                                         \
    for (int ct = 0; ct < 4; ++ct) {                                          \
        const f16x8 bh0 = *(const f16x8*)(pB0 + (RSEL) + ct * 2048);          \
        const f16x8 bh1 = *(const f16x8*)(pB1 + (RSEL) + ct * 2048);          \
        f32x4 a0 = {0.f, 0.f, 0.f, 0.f};                                      \
        f32x4 a1 = {0.f, 0.f, 0.f, 0.f};                                      \
        a0 = __builtin_amdgcn_mfma_f32_16x16x32_f16(a0f[0], bh0, a0, 0,0,0);  \
        a1 = __builtin_amdgcn_mfma_f32_16x16x32_f16(a1f[0], bh0, a1, 0,0,0);  \
        a0 = __builtin_amdgcn_mfma_f32_16x16x32_f16(a0f[1], bh1, a0, 0,0,0);  \
        a1 = __builtin_amdgcn_mfma_f32_16x16x32_f16(a1f[1], bh1, a1, 0,0,0);  \
        const float2 cn = *(const float2*)(pnlp + ct * 128);                  \
        const float civ    = cn.y;                                            \
        const float cnsciv = cn.x * civ;                                      \
        const float m2civ  = -2.0f * civ;                                     \
        const unsigned gcol = (unsigned)(jlx + itofs + ct * 16);              \
        const int dofs = itofs + ct * 16;                                     \
        _Pragma("unroll")                                                     \
        for (int r = 0; r < 4; ++r) {                                         \
            float q0 = fmaf(a0[r], m2civ, fmaf(rns0[r], civ, cnsciv));        \
            q0 = fmaxf(q0, 0.0f);                                             \
            unsigned k0 = (__float_as_uint(q0) & 0xFFFFE000u) | gcol;         \
            k0 = (dofs - r == dg) ? INIT32 : k0;                              \
            INS5(tk0[r], k0)                                                  \
            float q1 = fmaf(a1[r], m2civ, fmaf(rns1[r], civ, cnsciv));        \
            q1 = fmaxf(q1, 0.0f);                                             \
            unsigned k1 = (__float_as_uint(q1) & 0xFFFFE000u) | gcol;         \
            k1 = (dofs - r - 16 == dg) ? INIT32 : k1;                         \
            INS5(tk1[r], k1)                                                  \
        }                                                                     \
    }                                                                         \
    __builtin_amdgcn_s_setprio(0);                                            \
    itofs += 64;                                                              \
    pnlp  += 512;                                                             \
    asm volatile("" ::: "memory");                                            \
} while (0)

    // steady state t=0..5 (stage t+2, wait own tile with 4 newer in flight)
#pragma unroll 1
    for (int ip = 0; ip < 2; ++ip) {
        ITER(0,     16384, true, "4");   // t: buf0, stage -> buf2
        ITER(8192,  0,     true, "4");   // t: buf1, stage -> buf0
        ITER(16384, 8192,  true, "4");   // t: buf2, stage -> buf1
    }
    // epilogue t=6 (outstanding t6,t7), t=7 (outstanding t7)
    ITER(0,    0, false, "2");
    ITER(8192, 0, false, "0");
#undef ITER
#undef INS5

    // ---- in-register merge: 16 lanes x sorted-5 -> row top-5, 5 rounds of group-min ----
    // keys unique across lanes (col mod 16 == lx), so exactly the winner advances.
#define MERGE(TK, ROWOFS) do {                                                \
    _Pragma("unroll")                                                         \
    for (int r = 0; r < 4; ++r) {                                             \
        unsigned t5r[5];                                                      \
        _Pragma("unroll")                                                     \
        for (int s = 0; s < 5; ++s) t5r[s] = TK[r][s];                        \
        unsigned out = INIT32;                                                \
        unsigned h = t5r[0];                                                  \
        _Pragma("unroll")                                                     \
        for (int s = 0; s < 5; ++s) {                                         \
            unsigned m = group_minu32(h);                                     \
            if (lx == s) out = m;                                             \
            if (h == m) {                                                     \
                t5r[0] = t5r[1]; t5r[1] = t5r[2]; t5r[2] = t5r[3];            \
                t5r[3] = t5r[4]; t5r[4] = INIT32;                             \
                h = t5r[0];                                                   \
            }                                                                 \
        }                                                                     \
        if (lx < 5)                                                           \
            part[(size_t)(r0 + wv * 32 + lq * 4 + r + (ROWOFS)) * 80          \
                 + (size_t)ch * 5 + lx] = out;                                \
    }                                                                         \
} while (0)

    MERGE(tk0, 0);
    MERGE(tk1, 16);
#undef MERGE
}

// ---------------- Kernel 3: finalize, 4 rows/block (wave per row), shuffle-parallel ----------------
__global__ __launch_bounds__(256) void finalize_kernel(
        const float* __restrict__ X, const float2* __restrict__ nsiv,
        const unsigned* __restrict__ part, float* __restrict__ rowloss) {
    const int t = threadIdx.x, lane = t & 63, wv = t >> 6;
    const int row = blockIdx.x * 4 + wv;

    // merge chunk top-5s (80 u32 keys, 2 per lane) -> global top-5 via 5 wave-min passes
    const unsigned* prow = part + (size_t)row * 80;
    unsigned a0 = prow[lane];
    unsigned a1 = (lane < 16) ? prow[64 + lane] : INIT32;
    unsigned klo = (a0 < a1) ? a0 : a1;
    unsigned khi = (a0 < a1) ? a1 : a0;
    unsigned b[5];
#pragma unroll
    for (int s = 0; s < 5; ++s) {
        unsigned m = wave_minu32(klo);
        b[s] = m;
        if (klo == m) { klo = khi; khi = INIT32; }   // unique keys -> unique min
    }

    int pcol[5], ids[5];
#pragma unroll
    for (int s = 0; s < 5; ++s) { pcol[s] = (int)(b[s] & 8191u); ids[s] = pcol[s]; }
    // sort excluded ids ascending (tiny; every lane duplicates)
    for (int i = 0; i < 4; ++i)
        for (int j = 0; j < 4 - i; ++j)
            if (ids[j] > ids[j + 1]) { int tmp = ids[j]; ids[j] = ids[j + 1]; ids[j + 1] = tmp; }

    // column for this lane: lanes 0..19 = sampled negatives, 20..24 = positives
    int col = row;
    if (lane < 20) {
        unsigned m0 = (unsigned)(row * 20 + lane);
        unsigned hi, lo;
        threefry2x32(0u, 42u, m0, m0 + TOTAL_SAMP, hi, lo);
        unsigned samp = ((hi % SPAN) * MULT + (lo % SPAN)) % SPAN;
        int c = (int)samp;
#pragma unroll
        for (int s = 0; s < 5; ++s) c += (ids[s] <= c) ? 1 : 0;
        col = c;
    } else if (lane < 25) {
        col = pcol[lane - 20];
    }

    // exact fp32 Poincare distance term  -dist/tau  (diagonal -> -inf)
    float term = -INFINITY;
    if (lane < 25 && col != row) {
        const float4* xr = (const float4*)(X + (size_t)row * 64);
        const float4* xc = (const float4*)(X + (size_t)col * 64);
        float dot = 0.f;
#pragma unroll
        for (int k = 0; k < 16; ++k) {
            float4 a = xr[k];
            float4 c = xc[k];
            dot = fmaf(a.x, c.x, dot);
            dot = fmaf(a.y, c.y, dot);
            dot = fmaf(a.z, c.z, dot);
            dot = fmaf(a.w, c.w, dot);
        }
        float nsi = nsiv[row].x, nsj = nsiv[col].x;
        float d2  = fmaxf(nsi + nsj - 2.f * dot, 0.f);
        float ci  = 1.f - fminf(nsi, 1.f);
        float cj  = 1.f - fminf(nsj, 1.f);
        float den = fmaxf(ci * cj, 1e-9f);
        float z   = fmaxf(1.f + 2.f * d2 / den, 1.f);
        term = -acoshf(z) * TAU_INV;
    }

    // two masked LSEs across the wave
    float negt = (lane < 20) ? term : -INFINITY;
    float post = (lane >= 20 && lane < 25) ? term : -INFINITY;

    float nm = wave_maxf(negt);
    float ne = (lane < 20 && negt != -INFINITY) ? expf(negt - nm) : 0.f;
    float neg = nm + logf(wave_sumf(ne));

    float pm = wave_maxf(post);
    float pe = (lane >= 20 && lane < 25) ? expf(post - pm) : 0.f;
    float pos = pm + logf(wave_sumf(pe));

    if (lane == 0) rowloss[row] = neg - pos;
}

// ---------------- Kernel 4: deterministic tree sum ----------------
__global__ void reduce_kernel(const float* __restrict__ rl, float* __restrict__ out) {
    const int t = threadIdx.x;
    float s = 0.f;
#pragma unroll
    for (int i = 0; i < 32; ++i) s += rl[t + 256 * i];
#pragma unroll
    for (int o = 32; o; o >>= 1) s += __shfl_xor(s, o);
    __shared__ float ws4[4];
    if ((t & 63) == 0) ws4[t >> 6] = s;
    __syncthreads();
    if (t == 0) out[0] = (ws4[0] + ws4[1] + ws4[2] + ws4[3]) * (1.0f / 8192.0f);
}

// ---------------- launch ----------------
extern "C" void kernel_launch(void* const* d_in, const int* in_sizes, int n_in,
                              void* d_out, int out_size, void* d_ws, size_t ws_size,
                              hipStream_t stream) {
    (void)in_sizes; (void)n_in; (void)out_size; (void)ws_size;
    const float* X = (const float*)d_in[0];
    float* out = (float*)d_out;

    float2*   nsiv    = (float2*)d_ws;                                  // 64 KB
    char*     Xf      = (char*)d_ws + 65536;                            // 1 MB
    unsigned* part    = (unsigned*)((char*)d_ws + 65536 + 1048576);     // 2.62 MB (8192*80*4)
    float*    rowloss = (float*)((char*)d_ws + 65536 + 1048576 + 2621440); // 32 KB

    prep_kernel<<<256, 256, 0, stream>>>(X, nsiv, Xf);
    gram_topk<<<1024, 256, 0, stream>>>(Xf, nsiv, part);
    finalize_kernel<<<2048, 256, 0, stream>>>(X, nsiv, part, rowloss);
    reduce_kernel<<<1, 256, 0, stream>>>(rowloss, out);
}